// Round 3
// baseline (115.588 us; speedup 1.0000x reference)
//
#include <hip/hip_runtime.h>
#include <hip/hip_bf16.h>
#include <stdint.h>

// ---------------------------------------------------------------------------
// SNN: x[512,784] -> FC(784->1024)+LIF -> FC(1024->1024)+LIF -> FC(1024->10)+LIF
// T=32, tau=2, vth=1, hard reset. Out = spike counts [512,10].
//
// Verified (R5-R12, absmax=0): layer-0 LIF exactly periodic (class=ctz+1);
// layer-1 current = divisor sum over class weight-sums; cur0 = exact 3-way
// bf16-split (6 cross-terms hh,hm,mh,mm,hl,lh) MFMA GEMM.
//
// R16 = R15 resubmit (container infra failure, kernel never ran):
//   split-K 10 -> 5 (160 gemm blocks, K=960 each; Cpart round-trip
//   42 MB -> 21 MB; no more 2-gemm-block straggler CUs) and BK=64
//   double-chunk staging (two 32-K chunks per barrier pair, 32 KB LDS;
//   bit-identical MFMA order, half the vmcnt(0)+barrier drains).
// R14: prep stores unique h/m/l planes (row stride 2400), float4/ushort4.
//
// Structure:
//   prep_k:   bf16 splits of x & W0 (1200 blocks, vectorized)
//   gemm0t_k: split-K MFMA (blocks 0..159, global_load_lds staging) + W1
//             transpose (blocks 160..1183) filling idle CUs
//   tail_k:   compact0 + layer1 + layer2 fused per batch (~6us)
// ---------------------------------------------------------------------------

typedef __bf16 bf16x8 __attribute__((ext_vector_type(8)));
typedef float  f32x4  __attribute__((ext_vector_type(4)));
typedef unsigned short u16x4 __attribute__((ext_vector_type(4)));

__device__ __forceinline__ void gload16(const void* g, void* l) {
  __builtin_amdgcn_global_load_lds((const __attribute__((address_space(1))) void*)g,
                                   (__attribute__((address_space(3))) void*)l,
                                   16, 0, 0);
}

__device__ __forceinline__ void bsplit3(float v, __hip_bfloat16& h,
                                        __hip_bfloat16& m, __hip_bfloat16& l) {
  h = __float2bfloat16(v);
  float r1 = v - __bfloat162float(h);
  m = __float2bfloat16(r1);
  float r2 = r1 - __bfloat162float(m);
  l = __float2bfloat16(r2);
}

// ---------------- prep: bf16 splits of x & W0 (unique h/m/l planes) ---------
// Blocks [0,400): x rows (512*200 groups); [400,1200): W0 rows (1024*200).
// Per thread: float4 read of 4 source elems, 3x ushort4 stores (h,m,l planes
// at row*2400 + {0,800,1600} + k0). Pad k in [784,800) stays zero.
__global__ __launch_bounds__(256) void prep_k(const float* __restrict__ x,
                                              const float* __restrict__ W0,
                                              __hip_bfloat16* __restrict__ Ax,
                                              __hip_bfloat16* __restrict__ Bw) {
  const int bid = blockIdx.x, tid = threadIdx.x;
  const float* src;
  __hip_bfloat16* dst;
  int i;
  if (bid < 400) { i = bid * 256 + tid; src = x;  dst = Ax; }
  else           { i = (bid - 400) * 256 + tid; src = W0; dst = Bw; }
  const int row = i / 200;
  const int k0 = (i - row * 200) * 4;

  f32x4 v = {0.f, 0.f, 0.f, 0.f};
  if (k0 < 784)  // 784 % 4 == 0: a group never straddles the pad boundary
    v = *(const f32x4*)(src + (size_t)row * 784 + k0);

  u16x4 hv, mv, lv;
#pragma unroll
  for (int e = 0; e < 4; ++e) {
    __hip_bfloat16 h, m, l;
    bsplit3(v[e], h, m, l);
    hv[e] = __builtin_bit_cast(unsigned short, h);
    mv[e] = __builtin_bit_cast(unsigned short, m);
    lv[e] = __builtin_bit_cast(unsigned short, l);
  }
  __hip_bfloat16* p = dst + (size_t)row * 2400 + k0;
  *(u16x4*)(p)        = hv;
  *(u16x4*)(p + 800)  = mv;
  *(u16x4*)(p + 1600) = lv;
}

// ---------------- gemm0 split-K x5 (global_load_lds) + W1 transpose ---------
// Blocks [0,160): gemm, decode bx(4) x by(8) x bz(5), K=960 per z.
// Blocks [160,1184): W1 32x32 transpose tiles (overlap gemm CUs as co-tenants).
// Term order over K=4800 (6 segments of 800): hh,hm,mh,mm,hl,lh.
//   A plane per seg: {h,h,m,m,h,l} -> elem offsets {0,0,800,800,0,1600}
//   B plane per seg: {h,m,h,m,l,h} -> elem offsets {0,800,0,800,1600,0}
// LDS layout: As0[0,8K) Bs0[8K,16K) As1[16K,24K) Bs1[24K,32K).
__global__ __launch_bounds__(256, 2) void gemm0t_k(const __hip_bfloat16* __restrict__ A,
                                                   const __hip_bfloat16* __restrict__ B,
                                                   const float* __restrict__ W1,
                                                   float* __restrict__ W1T,
                                                   float* __restrict__ Cpart) {
  __shared__ __align__(16) char smem[32768];
  const int bid = blockIdx.x, tid = threadIdx.x;

  if (bid >= 160) {                       // ---- W1 transpose tiles ----
    float (*t)[33] = (float(*)[33])smem;  // 4.2 KB of the 32 KB
    int tt = bid - 160;
    int c0 = (tt & 31) * 32, r0 = (tt >> 5) * 32;
    int lx = tid & 31, ly = tid >> 5;     // 32 x 8
#pragma unroll
    for (int i = 0; i < 32; i += 8)
      t[ly + i][lx] = W1[(size_t)(r0 + ly + i) * 1024 + (c0 + lx)];
    __syncthreads();
#pragma unroll
    for (int i = 0; i < 32; i += 8)
      W1T[(size_t)(c0 + ly + i) * 1024 + (r0 + lx)] = t[lx][ly + i];
    return;
  }

  // ---- gemm blocks ----
  const int bx = bid & 3, by = (bid >> 2) & 7, bz = bid >> 5;   // bz in [0,5)
  const int wave = tid >> 6, lane = tid & 63, quad = lane >> 4, l16 = lane & 15;
  const int wm = (wave >> 1) * 64, wn = (wave & 1) * 64;
  const int mbase = bx * 128, nbase = by * 128, kbase = bz * 960;
  const int srow = lane >> 2;
  const int gq = (lane & 3) ^ ((lane >> 3) & 3);
  const int swz = (l16 >> 1) & 3;
  f32x4 acc[4][4] = {};
  for (int kk = kbase; kk < kbase + 960; kk += 64) {
#pragma unroll
    for (int c = 0; c < 2; ++c) {
      // per-32-chunk segment decode (800 % 32 == 0: a chunk never straddles)
      const int kc = kk + c * 32;
      const int seg = kc / 800;
      const int rem = kc - seg * 800;
      const int abase = (seg == 2 || seg == 3) ? 800 : (seg == 5 ? 1600 : 0);
      const int bbase = (seg == 1 || seg == 3) ? 800 : (seg == 4 ? 1600 : 0);
      const __hip_bfloat16* Ak = A + abase + rem;
      const __hip_bfloat16* Bk = B + bbase + rem;
#pragma unroll
      for (int r = 0; r < 2; ++r) {
        int grp = wave * 2 + r;
        gload16(Ak + (size_t)(mbase + grp * 16 + srow) * 2400 + gq * 8,
                (char*)smem + c * 16384 + grp * 1024);
        gload16(Bk + (size_t)(nbase + grp * 16 + srow) * 2400 + gq * 8,
                (char*)smem + c * 16384 + 8192 + grp * 1024);
      }
    }
    __syncthreads();
#pragma unroll
    for (int c = 0; c < 2; ++c) {
      const __bf16* Ab = (const __bf16*)(smem + c * 16384);
      const __bf16* Bb = (const __bf16*)(smem + c * 16384 + 8192);
      bf16x8 af[4], bfr[4];
#pragma unroll
      for (int i = 0; i < 4; ++i)
        af[i] = *(const bf16x8*)(Ab + (wm + i * 16 + l16) * 32 + ((quad ^ swz) * 8));
#pragma unroll
      for (int j = 0; j < 4; ++j)
        bfr[j] = *(const bf16x8*)(Bb + (wn + j * 16 + l16) * 32 + ((quad ^ swz) * 8));
      __builtin_amdgcn_s_setprio(1);
#pragma unroll
      for (int i = 0; i < 4; ++i)
#pragma unroll
        for (int j = 0; j < 4; ++j)
          acc[i][j] = __builtin_amdgcn_mfma_f32_16x16x32_bf16(af[i], bfr[j], acc[i][j], 0, 0, 0);
      __builtin_amdgcn_s_setprio(0);
    }
    __syncthreads();
  }
  float* Cz = Cpart + (size_t)bz * 512 * 1024;
#pragma unroll
  for (int i = 0; i < 4; ++i)
#pragma unroll
    for (int j = 0; j < 4; ++j)
#pragma unroll
      for (int r = 0; r < 4; ++r) {
        int m = mbase + wm + i * 16 + quad * 4 + r;
        int n = nbase + wn + j * 16 + l16;
        Cz[(size_t)m * 1024 + n] = acc[i][j][r];
      }
}

// ---------------- fused tail (compact0 + layer1 + layer2) -------------------
struct TailSM {
  unsigned short sidx[1024];
  int sseg[33];
  int mtot;
  unsigned l2i[1024];
  unsigned l2w[1024];
  union {
    struct { int whist[16][33]; int clstot[33]; int clsofs[34]; int wofs[16][33]; } s3;
    struct { int wtot[16]; int wbase[16]; } s4;
    struct { float sW2[10 * 1025]; float scur[320]; } s5;
  } u;
};

__global__ __launch_bounds__(1024) void tail_k(const float* __restrict__ Cpart,
                                               const float* __restrict__ b0,
                                               const float* __restrict__ W1T,
                                               const float* __restrict__ b1,
                                               const float* __restrict__ W2,
                                               const float* __restrict__ b2,
                                               float* __restrict__ out) {
  __shared__ TailSM sm;
  const int b = blockIdx.x, o = threadIdx.x;
  const int wave = o >> 6, lane = o & 63;

  // ---- S3: split-K reduce (5 slices) + LIF + class compaction ----
  {
    float cur = 0.f;
#pragma unroll
    for (int z = 0; z < 5; ++z)
      cur += Cpart[(size_t)z * 512 * 1024 + (size_t)b * 1024 + o];
    cur += b0[o];
    float v = 0.f;
    unsigned word = 0u;
#pragma unroll
    for (int t = 0; t < 32; ++t) {
      v = v + (cur - v) * 0.5f;            // exact: /2.0 == *0.5f
      if (v >= 1.0f) { word |= 1u << t; v = 0.f; }
    }
    int n = word ? (__builtin_ctz(word) + 1) : 0;
    unsigned long long mymask = 0ull;
#pragma unroll 1
    for (int c = 1; c <= 32; ++c) {
      unsigned long long m = __ballot(n == c);
      if (lane == 0) sm.u.s3.whist[wave][c] = __popcll(m);
      if (n == c) mymask = m;
    }
    __syncthreads();
    if (o < 32) {
      int c = o + 1, s = 0;
#pragma unroll
      for (int w = 0; w < 16; ++w) s += sm.u.s3.whist[w][c];
      sm.u.s3.clstot[c] = s;
    }
    __syncthreads();
    if (o == 0) {
      int run = 0;
#pragma unroll
      for (int c = 1; c <= 32; ++c) { sm.u.s3.clsofs[c] = run; run += sm.u.s3.clstot[c]; }
      sm.u.s3.clsofs[33] = run;
    }
    __syncthreads();
    if (o < 32) {
      int c = o + 1, s = sm.u.s3.clsofs[c];
#pragma unroll
      for (int w = 0; w < 16; ++w) { sm.u.s3.wofs[w][c] = s; s += sm.u.s3.whist[w][c]; }
    }
    __syncthreads();
    if (n) {
      int pos = sm.u.s3.wofs[wave][n] + __popcll(mymask & ((1ull << lane) - 1ull));
      sm.sidx[pos] = (unsigned short)o;
    }
    if (o < 33) sm.sseg[o] = sm.u.s3.clsofs[o + 1];
  }
  __syncthreads();

  // ---- S4: layer-1 class-sums + divisor LIF + compaction ----
  {
    float S[32];
#pragma unroll
    for (int c = 0; c < 32; ++c) {
      int j0 = __builtin_amdgcn_readfirstlane((c == 0) ? 0 : sm.sseg[c - 1]);
      int j1 = __builtin_amdgcn_readfirstlane(sm.sseg[c]);
      float s = 0.f;
      for (int j = j0; j < j1; ++j)
        s += W1T[(size_t)sm.sidx[j] * 1024 + o];
      S[c] = s;
    }
    const float bias = b1[o];
    float v = 0.f;
    unsigned word = 0u;
#pragma unroll
    for (int t = 0; t < 32; ++t) {
      float cur = 0.f;
#pragma unroll
      for (int c = 1; c <= 32; ++c)
        if ((t + 1) % c == 0) cur += S[c - 1];   // compile-time divisor table
      float xc = cur + bias;
      v = v + (xc - v) * 0.5f;
      if (v >= 1.0f) { word |= 1u << t; v = 0.f; }
    }
    bool act = (word != 0u);
    unsigned long long m = __ballot(act);
    if (lane == 0) sm.u.s4.wtot[wave] = __popcll(m);
    __syncthreads();
    if (o == 0) {
      int s = 0;
#pragma unroll
      for (int i = 0; i < 16; ++i) { sm.u.s4.wbase[i] = s; s += sm.u.s4.wtot[i]; }
      sm.mtot = s;
    }
    __syncthreads();
    if (act) {
      int pos = sm.u.s4.wbase[wave] + __popcll(m & ((1ull << lane) - 1ull));
      sm.l2i[pos] = (unsigned)o;
      sm.l2w[pos] = word;
    }
  }
  __syncthreads();

  // ---- S5: layer-2 sparse FC + LIF + count ----
  {
    for (int i = o; i < 10240; i += 1024)
      sm.u.s5.sW2[(i >> 10) * 1025 + (i & 1023)] = W2[i];
    __syncthreads();
    const int mtot = sm.mtot;
    if (o < 320) {
      int t = o / 10, c = o - t * 10;
      float acc = 0.f;
      for (int j = 0; j < mtot; ++j) {
        unsigned wd = sm.l2w[j];
        float wv = sm.u.s5.sW2[c * 1025 + sm.l2i[j]];
        acc += ((wd >> t) & 1u) ? wv : 0.f;
      }
      sm.u.s5.scur[o] = acc;
    }
    __syncthreads();
    if (o < 10) {
      float v = 0.f, cnt2 = 0.f, bias = b2[o];
#pragma unroll
      for (int tt = 0; tt < 32; ++tt) {
        float xc = sm.u.s5.scur[tt * 10 + o] + bias;
        v = v + (xc - v) * 0.5f;
        if (v >= 1.0f) { cnt2 += 1.f; v = 0.f; }
      }
      out[(size_t)b * 10 + o] = cnt2;
    }
  }
}

// ---------------------------------------------------------------------------
extern "C" void kernel_launch(void* const* d_in, const int* in_sizes, int n_in,
                              void* d_out, int out_size, void* d_ws, size_t ws_size,
                              hipStream_t stream) {
  const float* x  = (const float*)d_in[0];   // [512,784]
  const float* W0 = (const float*)d_in[1];   // [1024,784]
  const float* b0 = (const float*)d_in[2];   // [1024]
  const float* W1 = (const float*)d_in[3];   // [1024,1024]
  const float* b1 = (const float*)d_in[4];   // [1024]
  const float* W2 = (const float*)d_in[5];   // [10,1024]
  const float* b2 = (const float*)d_in[6];   // [10]
  float* out = (float*)d_out;                // [512,10]

  char* ws = (char*)d_ws;
  size_t off = 0;
  auto alloc = [&](size_t bytes) -> char* {
    char* p = ws + off;
    off += (bytes + 255) & ~(size_t)255;
    return p;
  };
  __hip_bfloat16* Ax    = (__hip_bfloat16*)alloc((size_t)512 * 2400 * 2);   // 2.4 MB
  __hip_bfloat16* Bw    = (__hip_bfloat16*)alloc((size_t)1024 * 2400 * 2);  // 4.9 MB
  float*          Cpart = (float*)alloc((size_t)5 * 512 * 1024 * 4);        // 10.5 MB
  float*          W1T   = (float*)alloc((size_t)1024 * 1024 * 4);           // 4.2 MB
  (void)ws_size;

  prep_k<<<1200, 256, 0, stream>>>(x, W0, Ax, Bw);
  gemm0t_k<<<1184, 256, 0, stream>>>(Ax, Bw, W1, W1T, Cpart);
  tail_k<<<512, 1024, 0, stream>>>(Cpart, b0, W1T, b1, W2, b2, out);
}

// Round 4
// 115.534 us; speedup vs baseline: 1.0005x; 1.0005x over previous
//
#include <hip/hip_runtime.h>
#include <hip/hip_bf16.h>
#include <stdint.h>

// ---------------------------------------------------------------------------
// SNN: x[512,784] -> FC(784->1024)+LIF -> FC(1024->1024)+LIF -> FC(1024->10)+LIF
// T=32, tau=2, vth=1, hard reset. Out = spike counts [512,10].
//
// Verified (R5-R12, absmax=0): layer-0 LIF exactly periodic (class=ctz+1);
// layer-1 current = divisor sum over class weight-sums; cur0 = exact 3-way
// bf16-split (6 cross-terms hh,hm,mh,mm,hl,lh) MFMA GEMM.
//
// R17 (this round): split-K 6 x K=800, BK=32 (R1 inner loop VERBATIM).
//   - 192 gemm blocks <= 256 CUs: no straggler CUs (R1: 320 blocks -> 64 CUs
//     ran 2 gemm blocks, critical path 30 iters; now 25).
//   - each z-slice == one 800-wide segment: plane offsets are per-block
//     constants, no per-iteration segment decode.
//   - Cpart round trip 21+21 -> 12.6+12.6 MB; tail reduce 10 -> 6 loads.
//   R3's splitK5+BK64 regressed (115.6); BK=64 is abandoned, BK=32 restored.
// R14: prep stores unique h/m/l planes (row stride 2400), float4/ushort4.
//
// Structure:
//   prep_k:   bf16 splits of x & W0 (1200 blocks, vectorized)
//   gemm0t_k: split-K MFMA (blocks 0..191, global_load_lds staging) + W1
//             transpose (blocks 192..1215) filling idle CUs
//   tail_k:   compact0 + layer1 + layer2 fused per batch (~6us)
// ---------------------------------------------------------------------------

typedef __bf16 bf16x8 __attribute__((ext_vector_type(8)));
typedef float  f32x4  __attribute__((ext_vector_type(4)));
typedef unsigned short u16x4 __attribute__((ext_vector_type(4)));

__device__ __forceinline__ void gload16(const void* g, void* l) {
  __builtin_amdgcn_global_load_lds((const __attribute__((address_space(1))) void*)g,
                                   (__attribute__((address_space(3))) void*)l,
                                   16, 0, 0);
}

__device__ __forceinline__ void bsplit3(float v, __hip_bfloat16& h,
                                        __hip_bfloat16& m, __hip_bfloat16& l) {
  h = __float2bfloat16(v);
  float r1 = v - __bfloat162float(h);
  m = __float2bfloat16(r1);
  float r2 = r1 - __bfloat162float(m);
  l = __float2bfloat16(r2);
}

// ---------------- prep: bf16 splits of x & W0 (unique h/m/l planes) ---------
// Blocks [0,400): x rows (512*200 groups); [400,1200): W0 rows (1024*200).
// Per thread: float4 read of 4 source elems, 3x ushort4 stores (h,m,l planes
// at row*2400 + {0,800,1600} + k0). Pad k in [784,800) stays zero.
__global__ __launch_bounds__(256) void prep_k(const float* __restrict__ x,
                                              const float* __restrict__ W0,
                                              __hip_bfloat16* __restrict__ Ax,
                                              __hip_bfloat16* __restrict__ Bw) {
  const int bid = blockIdx.x, tid = threadIdx.x;
  const float* src;
  __hip_bfloat16* dst;
  int i;
  if (bid < 400) { i = bid * 256 + tid; src = x;  dst = Ax; }
  else           { i = (bid - 400) * 256 + tid; src = W0; dst = Bw; }
  const int row = i / 200;
  const int k0 = (i - row * 200) * 4;

  f32x4 v = {0.f, 0.f, 0.f, 0.f};
  if (k0 < 784)  // 784 % 4 == 0: a group never straddles the pad boundary
    v = *(const f32x4*)(src + (size_t)row * 784 + k0);

  u16x4 hv, mv, lv;
#pragma unroll
  for (int e = 0; e < 4; ++e) {
    __hip_bfloat16 h, m, l;
    bsplit3(v[e], h, m, l);
    hv[e] = __builtin_bit_cast(unsigned short, h);
    mv[e] = __builtin_bit_cast(unsigned short, m);
    lv[e] = __builtin_bit_cast(unsigned short, l);
  }
  __hip_bfloat16* p = dst + (size_t)row * 2400 + k0;
  *(u16x4*)(p)        = hv;
  *(u16x4*)(p + 800)  = mv;
  *(u16x4*)(p + 1600) = lv;
}

// ---------------- gemm0 split-K x6 (global_load_lds) + W1 transpose ---------
// Blocks [0,192): gemm, decode bx(4) x by(8) x bz(6); z-slice = segment bz,
// K=800, BK=32, 25 iterations. Term order (6 segments of 800): hh,hm,mh,mm,hl,lh.
//   A plane per seg: {h,h,m,m,h,l} -> elem offsets {0,0,800,800,0,1600}
//   B plane per seg: {h,m,h,m,l,h} -> elem offsets {0,800,0,800,1600,0}
// Blocks [192,1216): W1 32x32 transpose tiles (overlap gemm CUs as co-tenants).
__global__ __launch_bounds__(256, 2) void gemm0t_k(const __hip_bfloat16* __restrict__ A,
                                                   const __hip_bfloat16* __restrict__ B,
                                                   const float* __restrict__ W1,
                                                   float* __restrict__ W1T,
                                                   float* __restrict__ Cpart) {
  __shared__ __align__(16) char smem[16384];
  const int bid = blockIdx.x, tid = threadIdx.x;

  if (bid >= 192) {                       // ---- W1 transpose tiles ----
    float (*t)[33] = (float(*)[33])smem;  // 4.2 KB of the 16 KB
    int tt = bid - 192;
    int c0 = (tt & 31) * 32, r0 = (tt >> 5) * 32;
    int lx = tid & 31, ly = tid >> 5;     // 32 x 8
#pragma unroll
    for (int i = 0; i < 32; i += 8)
      t[ly + i][lx] = W1[(size_t)(r0 + ly + i) * 1024 + (c0 + lx)];
    __syncthreads();
#pragma unroll
    for (int i = 0; i < 32; i += 8)
      W1T[(size_t)(c0 + ly + i) * 1024 + (r0 + lx)] = t[lx][ly + i];
    return;
  }

  // ---- gemm blocks (R1 inner loop, constant plane offsets) ----
  __hip_bfloat16* As = (__hip_bfloat16*)smem;
  __hip_bfloat16* Bs = As + 128 * 32;
  const int bx = bid & 3, by = (bid >> 2) & 7, bz = bid >> 5;   // bz in [0,6)
  const int wave = tid >> 6, lane = tid & 63, quad = lane >> 4, l16 = lane & 15;
  const int wm = (wave >> 1) * 64, wn = (wave & 1) * 64;
  const int mbase = bx * 128, nbase = by * 128;
  const int srow = lane >> 2;
  const int gq = (lane & 3) ^ ((lane >> 3) & 3);
  const int swz = (l16 >> 1) & 3;
  // per-block constant plane offsets (z-slice == segment bz)
  const int abase = (bz == 2 || bz == 3) ? 800 : (bz == 5 ? 1600 : 0);
  const int bbase = (bz == 1 || bz == 3) ? 800 : (bz == 4 ? 1600 : 0);
  const __hip_bfloat16* Ak = A + abase;
  const __hip_bfloat16* Bk = B + bbase;
  f32x4 acc[4][4] = {};
  for (int kk = 0; kk < 800; kk += 32) {
#pragma unroll
    for (int r = 0; r < 2; ++r) {
      int grp = wave * 2 + r;
      gload16(Ak + (size_t)(mbase + grp * 16 + srow) * 2400 + kk + gq * 8,
              (char*)As + grp * 1024);
      gload16(Bk + (size_t)(nbase + grp * 16 + srow) * 2400 + kk + gq * 8,
              (char*)Bs + grp * 1024);
    }
    __syncthreads();
    const __bf16* Ab = (const __bf16*)As;
    const __bf16* Bb = (const __bf16*)Bs;
    bf16x8 af[4], bfr[4];
#pragma unroll
    for (int i = 0; i < 4; ++i)
      af[i] = *(const bf16x8*)(Ab + (wm + i * 16 + l16) * 32 + ((quad ^ swz) * 8));
#pragma unroll
    for (int j = 0; j < 4; ++j)
      bfr[j] = *(const bf16x8*)(Bb + (wn + j * 16 + l16) * 32 + ((quad ^ swz) * 8));
    __builtin_amdgcn_s_setprio(1);
#pragma unroll
    for (int i = 0; i < 4; ++i)
#pragma unroll
      for (int j = 0; j < 4; ++j)
        acc[i][j] = __builtin_amdgcn_mfma_f32_16x16x32_bf16(af[i], bfr[j], acc[i][j], 0, 0, 0);
    __builtin_amdgcn_s_setprio(0);
    __syncthreads();
  }
  float* Cz = Cpart + (size_t)bz * 512 * 1024;
#pragma unroll
  for (int i = 0; i < 4; ++i)
#pragma unroll
    for (int j = 0; j < 4; ++j)
#pragma unroll
      for (int r = 0; r < 4; ++r) {
        int m = mbase + wm + i * 16 + quad * 4 + r;
        int n = nbase + wn + j * 16 + l16;
        Cz[(size_t)m * 1024 + n] = acc[i][j][r];
      }
}

// ---------------- fused tail (compact0 + layer1 + layer2) -------------------
struct TailSM {
  unsigned short sidx[1024];
  int sseg[33];
  int mtot;
  unsigned l2i[1024];
  unsigned l2w[1024];
  union {
    struct { int whist[16][33]; int clstot[33]; int clsofs[34]; int wofs[16][33]; } s3;
    struct { int wtot[16]; int wbase[16]; } s4;
    struct { float sW2[10 * 1025]; float scur[320]; } s5;
  } u;
};

__global__ __launch_bounds__(1024) void tail_k(const float* __restrict__ Cpart,
                                               const float* __restrict__ b0,
                                               const float* __restrict__ W1T,
                                               const float* __restrict__ b1,
                                               const float* __restrict__ W2,
                                               const float* __restrict__ b2,
                                               float* __restrict__ out) {
  __shared__ TailSM sm;
  const int b = blockIdx.x, o = threadIdx.x;
  const int wave = o >> 6, lane = o & 63;

  // ---- S3: split-K reduce (6 slices) + LIF + class compaction ----
  {
    float cur = 0.f;
#pragma unroll
    for (int z = 0; z < 6; ++z)
      cur += Cpart[(size_t)z * 512 * 1024 + (size_t)b * 1024 + o];
    cur += b0[o];
    float v = 0.f;
    unsigned word = 0u;
#pragma unroll
    for (int t = 0; t < 32; ++t) {
      v = v + (cur - v) * 0.5f;            // exact: /2.0 == *0.5f
      if (v >= 1.0f) { word |= 1u << t; v = 0.f; }
    }
    int n = word ? (__builtin_ctz(word) + 1) : 0;
    unsigned long long mymask = 0ull;
#pragma unroll 1
    for (int c = 1; c <= 32; ++c) {
      unsigned long long m = __ballot(n == c);
      if (lane == 0) sm.u.s3.whist[wave][c] = __popcll(m);
      if (n == c) mymask = m;
    }
    __syncthreads();
    if (o < 32) {
      int c = o + 1, s = 0;
#pragma unroll
      for (int w = 0; w < 16; ++w) s += sm.u.s3.whist[w][c];
      sm.u.s3.clstot[c] = s;
    }
    __syncthreads();
    if (o == 0) {
      int run = 0;
#pragma unroll
      for (int c = 1; c <= 32; ++c) { sm.u.s3.clsofs[c] = run; run += sm.u.s3.clstot[c]; }
      sm.u.s3.clsofs[33] = run;
    }
    __syncthreads();
    if (o < 32) {
      int c = o + 1, s = sm.u.s3.clsofs[c];
#pragma unroll
      for (int w = 0; w < 16; ++w) { sm.u.s3.wofs[w][c] = s; s += sm.u.s3.whist[w][c]; }
    }
    __syncthreads();
    if (n) {
      int pos = sm.u.s3.wofs[wave][n] + __popcll(mymask & ((1ull << lane) - 1ull));
      sm.sidx[pos] = (unsigned short)o;
    }
    if (o < 33) sm.sseg[o] = sm.u.s3.clsofs[o + 1];
  }
  __syncthreads();

  // ---- S4: layer-1 class-sums + divisor LIF + compaction ----
  {
    float S[32];
#pragma unroll
    for (int c = 0; c < 32; ++c) {
      int j0 = __builtin_amdgcn_readfirstlane((c == 0) ? 0 : sm.sseg[c - 1]);
      int j1 = __builtin_amdgcn_readfirstlane(sm.sseg[c]);
      float s = 0.f;
      for (int j = j0; j < j1; ++j)
        s += W1T[(size_t)sm.sidx[j] * 1024 + o];
      S[c] = s;
    }
    const float bias = b1[o];
    float v = 0.f;
    unsigned word = 0u;
#pragma unroll
    for (int t = 0; t < 32; ++t) {
      float cur = 0.f;
#pragma unroll
      for (int c = 1; c <= 32; ++c)
        if ((t + 1) % c == 0) cur += S[c - 1];   // compile-time divisor table
      float xc = cur + bias;
      v = v + (xc - v) * 0.5f;
      if (v >= 1.0f) { word |= 1u << t; v = 0.f; }
    }
    bool act = (word != 0u);
    unsigned long long m = __ballot(act);
    if (lane == 0) sm.u.s4.wtot[wave] = __popcll(m);
    __syncthreads();
    if (o == 0) {
      int s = 0;
#pragma unroll
      for (int i = 0; i < 16; ++i) { sm.u.s4.wbase[i] = s; s += sm.u.s4.wtot[i]; }
      sm.mtot = s;
    }
    __syncthreads();
    if (act) {
      int pos = sm.u.s4.wbase[wave] + __popcll(m & ((1ull << lane) - 1ull));
      sm.l2i[pos] = (unsigned)o;
      sm.l2w[pos] = word;
    }
  }
  __syncthreads();

  // ---- S5: layer-2 sparse FC + LIF + count ----
  {
    for (int i = o; i < 10240; i += 1024)
      sm.u.s5.sW2[(i >> 10) * 1025 + (i & 1023)] = W2[i];
    __syncthreads();
    const int mtot = sm.mtot;
    if (o < 320) {
      int t = o / 10, c = o - t * 10;
      float acc = 0.f;
      for (int j = 0; j < mtot; ++j) {
        unsigned wd = sm.l2w[j];
        float wv = sm.u.s5.sW2[c * 1025 + sm.l2i[j]];
        acc += ((wd >> t) & 1u) ? wv : 0.f;
      }
      sm.u.s5.scur[o] = acc;
    }
    __syncthreads();
    if (o < 10) {
      float v = 0.f, cnt2 = 0.f, bias = b2[o];
#pragma unroll
      for (int tt = 0; tt < 32; ++tt) {
        float xc = sm.u.s5.scur[tt * 10 + o] + bias;
        v = v + (xc - v) * 0.5f;
        if (v >= 1.0f) { cnt2 += 1.f; v = 0.f; }
      }
      out[(size_t)b * 10 + o] = cnt2;
    }
  }
}

// ---------------------------------------------------------------------------
extern "C" void kernel_launch(void* const* d_in, const int* in_sizes, int n_in,
                              void* d_out, int out_size, void* d_ws, size_t ws_size,
                              hipStream_t stream) {
  const float* x  = (const float*)d_in[0];   // [512,784]
  const float* W0 = (const float*)d_in[1];   // [1024,784]
  const float* b0 = (const float*)d_in[2];   // [1024]
  const float* W1 = (const float*)d_in[3];   // [1024,1024]
  const float* b1 = (const float*)d_in[4];   // [1024]
  const float* W2 = (const float*)d_in[5];   // [10,1024]
  const float* b2 = (const float*)d_in[6];   // [10]
  float* out = (float*)d_out;                // [512,10]

  char* ws = (char*)d_ws;
  size_t off = 0;
  auto alloc = [&](size_t bytes) -> char* {
    char* p = ws + off;
    off += (bytes + 255) & ~(size_t)255;
    return p;
  };
  __hip_bfloat16* Ax    = (__hip_bfloat16*)alloc((size_t)512 * 2400 * 2);   // 2.4 MB
  __hip_bfloat16* Bw    = (__hip_bfloat16*)alloc((size_t)1024 * 2400 * 2);  // 4.9 MB
  float*          Cpart = (float*)alloc((size_t)6 * 512 * 1024 * 4);        // 12.6 MB
  float*          W1T   = (float*)alloc((size_t)1024 * 1024 * 4);           // 4.2 MB
  (void)ws_size;

  prep_k<<<1200, 256, 0, stream>>>(x, W0, Ax, Bw);
  gemm0t_k<<<1216, 256, 0, stream>>>(Ax, Bw, W1, W1T, Cpart);
  tail_k<<<512, 1024, 0, stream>>>(Cpart, b0, W1T, b1, W2, b2, out);
}

// Round 5
// 107.644 us; speedup vs baseline: 1.0738x; 1.0733x over previous
//
#include <hip/hip_runtime.h>
#include <hip/hip_bf16.h>
#include <stdint.h>

// ---------------------------------------------------------------------------
// SNN: x[512,784] -> FC(784->1024)+LIF -> FC(1024->1024)+LIF -> FC(1024->10)+LIF
// T=32, tau=2, vth=1, hard reset. Out = spike counts [512,10].
//
// Verified (R5-R12, absmax=0): layer-0 LIF exactly periodic (class=ctz+1);
// layer-1 current = divisor sum over class weight-sums; cur0 = exact 3-way
// bf16-split (6 cross-terms hh,hm,mh,mm,hl,lh) MFMA GEMM, split-K x10.
//
// R18 (this round): R1 config restored VERBATIM (splitK10/BK32/320 gemm +
//   1024 transpose blocks — measured 110.4/110.7; R3/R4 proved FEWER gemm
//   blocks regress ~5us: two co-resident gemm blocks per CU mutually hide
//   load latency) + depth-2 LDS double-buffer prefetch: issue next chunk's
//   global_load_lds before computing current chunk; in-loop __syncthreads
//   (compiler vmcnt(0)) drains it. Per-iter: load+compute -> max(load,
//   compute). Bit-identical MFMA order.
// R14: prep stores unique h/m/l planes (row stride 2400), float4/ushort4.
//
// Structure:
//   prep_k:   bf16 splits of x & W0 (1200 blocks, vectorized)
//   gemm0t_k: split-K MFMA (blocks 0..319, global_load_lds staging, dbuf) +
//             W1 transpose (blocks 320..1343) filling idle CUs
//   tail_k:   compact0 + layer1 + layer2 fused per batch (~6us)
// ---------------------------------------------------------------------------

typedef __bf16 bf16x8 __attribute__((ext_vector_type(8)));
typedef float  f32x4  __attribute__((ext_vector_type(4)));
typedef unsigned short u16x4 __attribute__((ext_vector_type(4)));

__device__ __forceinline__ void gload16(const void* g, void* l) {
  __builtin_amdgcn_global_load_lds((const __attribute__((address_space(1))) void*)g,
                                   (__attribute__((address_space(3))) void*)l,
                                   16, 0, 0);
}

__device__ __forceinline__ void bsplit3(float v, __hip_bfloat16& h,
                                        __hip_bfloat16& m, __hip_bfloat16& l) {
  h = __float2bfloat16(v);
  float r1 = v - __bfloat162float(h);
  m = __float2bfloat16(r1);
  float r2 = r1 - __bfloat162float(m);
  l = __float2bfloat16(r2);
}

// ---------------- prep: bf16 splits of x & W0 (unique h/m/l planes) ---------
// Blocks [0,400): x rows (512*200 groups); [400,1200): W0 rows (1024*200).
// Per thread: float4 read of 4 source elems, 3x ushort4 stores (h,m,l planes
// at row*2400 + {0,800,1600} + k0). Pad k in [784,800) stays zero.
__global__ __launch_bounds__(256) void prep_k(const float* __restrict__ x,
                                              const float* __restrict__ W0,
                                              __hip_bfloat16* __restrict__ Ax,
                                              __hip_bfloat16* __restrict__ Bw) {
  const int bid = blockIdx.x, tid = threadIdx.x;
  const float* src;
  __hip_bfloat16* dst;
  int i;
  if (bid < 400) { i = bid * 256 + tid; src = x;  dst = Ax; }
  else           { i = (bid - 400) * 256 + tid; src = W0; dst = Bw; }
  const int row = i / 200;
  const int k0 = (i - row * 200) * 4;

  f32x4 v = {0.f, 0.f, 0.f, 0.f};
  if (k0 < 784)  // 784 % 4 == 0: a group never straddles the pad boundary
    v = *(const f32x4*)(src + (size_t)row * 784 + k0);

  u16x4 hv, mv, lv;
#pragma unroll
  for (int e = 0; e < 4; ++e) {
    __hip_bfloat16 h, m, l;
    bsplit3(v[e], h, m, l);
    hv[e] = __builtin_bit_cast(unsigned short, h);
    mv[e] = __builtin_bit_cast(unsigned short, m);
    lv[e] = __builtin_bit_cast(unsigned short, l);
  }
  __hip_bfloat16* p = dst + (size_t)row * 2400 + k0;
  *(u16x4*)(p)        = hv;
  *(u16x4*)(p + 800)  = mv;
  *(u16x4*)(p + 1600) = lv;
}

// ---------------- gemm0 split-K x10 (dbuf prefetch) + W1 transpose ----------
// Blocks [0,320): gemm, decode bx(4) x by(8) x bz(10), K=480 per z, BK=32.
// Blocks [320,1344): W1 32x32 transpose tiles (overlap gemm CUs as co-tenants).
// Term order over K=4800 (6 segments of 800): hh,hm,mh,mm,hl,lh.
//   A plane per seg: {h,h,m,m,h,l} -> elem offsets {0,0,800,800,0,1600}
//   B plane per seg: {h,m,h,m,l,h} -> elem offsets {0,800,0,800,1600,0}
// LDS: buf0 [0,16K) = As|Bs, buf1 [16K,32K). Depth-2 prefetch: stage chunk
// k+32 into buf^1 before computing buf; __syncthreads drains (vmcnt0).
__global__ __launch_bounds__(256, 2) void gemm0t_k(const __hip_bfloat16* __restrict__ A,
                                                   const __hip_bfloat16* __restrict__ B,
                                                   const float* __restrict__ W1,
                                                   float* __restrict__ W1T,
                                                   float* __restrict__ Cpart) {
  __shared__ __align__(16) char smem[32768];
  const int bid = blockIdx.x, tid = threadIdx.x;

  if (bid >= 320) {                       // ---- W1 transpose tiles ----
    float (*t)[33] = (float(*)[33])smem;  // 4.2 KB of the 32 KB
    int tt = bid - 320;
    int c0 = (tt & 31) * 32, r0 = (tt >> 5) * 32;
    int lx = tid & 31, ly = tid >> 5;     // 32 x 8
#pragma unroll
    for (int i = 0; i < 32; i += 8)
      t[ly + i][lx] = W1[(size_t)(r0 + ly + i) * 1024 + (c0 + lx)];
    __syncthreads();
#pragma unroll
    for (int i = 0; i < 32; i += 8)
      W1T[(size_t)(c0 + ly + i) * 1024 + (r0 + lx)] = t[lx][ly + i];
    return;
  }

  // ---- gemm blocks ----
  const int bx = bid & 3, by = (bid >> 2) & 7, bz = bid >> 5;   // bz in [0,10)
  const int wave = tid >> 6, lane = tid & 63, quad = lane >> 4, l16 = lane & 15;
  const int wm = (wave >> 1) * 64, wn = (wave & 1) * 64;
  const int mbase = bx * 128, nbase = by * 128, kbase = bz * 480;
  const int srow = lane >> 2;
  const int gq = (lane & 3) ^ ((lane >> 3) & 3);
  const int swz = (l16 >> 1) & 3;

  auto stage = [&](int kc, int buf) {
    // per-chunk segment decode (800 % 32 == 0: a 32-chunk never straddles)
    const int seg = kc / 800;
    const int rem = kc - seg * 800;
    const int abase = (seg == 2 || seg == 3) ? 800 : (seg == 5 ? 1600 : 0);
    const int bbase = (seg == 1 || seg == 3) ? 800 : (seg == 4 ? 1600 : 0);
    const __hip_bfloat16* Ak = A + abase + rem;
    const __hip_bfloat16* Bk = B + bbase + rem;
#pragma unroll
    for (int r = 0; r < 2; ++r) {
      int grp = wave * 2 + r;
      gload16(Ak + (size_t)(mbase + grp * 16 + srow) * 2400 + gq * 8,
              (char*)smem + buf * 16384 + grp * 1024);
      gload16(Bk + (size_t)(nbase + grp * 16 + srow) * 2400 + gq * 8,
              (char*)smem + buf * 16384 + 8192 + grp * 1024);
    }
  };

  f32x4 acc[4][4] = {};
  stage(kbase, 0);
  __syncthreads();                        // drains buf0 (compiler vmcnt0)
  int cur = 0;
  for (int kk = kbase; kk < kbase + 480; kk += 32) {
    if (kk + 32 < kbase + 480) stage(kk + 32, cur ^ 1);   // prefetch next
    const __bf16* Ab = (const __bf16*)(smem + cur * 16384);
    const __bf16* Bb = (const __bf16*)(smem + cur * 16384 + 8192);
    bf16x8 af[4], bfr[4];
#pragma unroll
    for (int i = 0; i < 4; ++i)
      af[i] = *(const bf16x8*)(Ab + (wm + i * 16 + l16) * 32 + ((quad ^ swz) * 8));
#pragma unroll
    for (int j = 0; j < 4; ++j)
      bfr[j] = *(const bf16x8*)(Bb + (wn + j * 16 + l16) * 32 + ((quad ^ swz) * 8));
    __builtin_amdgcn_s_setprio(1);
#pragma unroll
    for (int i = 0; i < 4; ++i)
#pragma unroll
      for (int j = 0; j < 4; ++j)
        acc[i][j] = __builtin_amdgcn_mfma_f32_16x16x32_bf16(af[i], bfr[j], acc[i][j], 0, 0, 0);
    __builtin_amdgcn_s_setprio(0);
    __syncthreads();                      // drains prefetch + protects reuse
    cur ^= 1;
  }
  float* Cz = Cpart + (size_t)bz * 512 * 1024;
#pragma unroll
  for (int i = 0; i < 4; ++i)
#pragma unroll
    for (int j = 0; j < 4; ++j)
#pragma unroll
      for (int r = 0; r < 4; ++r) {
        int m = mbase + wm + i * 16 + quad * 4 + r;
        int n = nbase + wn + j * 16 + l16;
        Cz[(size_t)m * 1024 + n] = acc[i][j][r];
      }
}

// ---------------- fused tail (compact0 + layer1 + layer2) -------------------
struct TailSM {
  unsigned short sidx[1024];
  int sseg[33];
  int mtot;
  unsigned l2i[1024];
  unsigned l2w[1024];
  union {
    struct { int whist[16][33]; int clstot[33]; int clsofs[34]; int wofs[16][33]; } s3;
    struct { int wtot[16]; int wbase[16]; } s4;
    struct { float sW2[10 * 1025]; float scur[320]; } s5;
  } u;
};

__global__ __launch_bounds__(1024) void tail_k(const float* __restrict__ Cpart,
                                               const float* __restrict__ b0,
                                               const float* __restrict__ W1T,
                                               const float* __restrict__ b1,
                                               const float* __restrict__ W2,
                                               const float* __restrict__ b2,
                                               float* __restrict__ out) {
  __shared__ TailSM sm;
  const int b = blockIdx.x, o = threadIdx.x;
  const int wave = o >> 6, lane = o & 63;

  // ---- S3: split-K reduce (10 slices) + LIF + class compaction ----
  {
    float cur = 0.f;
#pragma unroll
    for (int z = 0; z < 10; ++z)
      cur += Cpart[(size_t)z * 512 * 1024 + (size_t)b * 1024 + o];
    cur += b0[o];
    float v = 0.f;
    unsigned word = 0u;
#pragma unroll
    for (int t = 0; t < 32; ++t) {
      v = v + (cur - v) * 0.5f;            // exact: /2.0 == *0.5f
      if (v >= 1.0f) { word |= 1u << t; v = 0.f; }
    }
    int n = word ? (__builtin_ctz(word) + 1) : 0;
    unsigned long long mymask = 0ull;
#pragma unroll 1
    for (int c = 1; c <= 32; ++c) {
      unsigned long long m = __ballot(n == c);
      if (lane == 0) sm.u.s3.whist[wave][c] = __popcll(m);
      if (n == c) mymask = m;
    }
    __syncthreads();
    if (o < 32) {
      int c = o + 1, s = 0;
#pragma unroll
      for (int w = 0; w < 16; ++w) s += sm.u.s3.whist[w][c];
      sm.u.s3.clstot[c] = s;
    }
    __syncthreads();
    if (o == 0) {
      int run = 0;
#pragma unroll
      for (int c = 1; c <= 32; ++c) { sm.u.s3.clsofs[c] = run; run += sm.u.s3.clstot[c]; }
      sm.u.s3.clsofs[33] = run;
    }
    __syncthreads();
    if (o < 32) {
      int c = o + 1, s = sm.u.s3.clsofs[c];
#pragma unroll
      for (int w = 0; w < 16; ++w) { sm.u.s3.wofs[w][c] = s; s += sm.u.s3.whist[w][c]; }
    }
    __syncthreads();
    if (n) {
      int pos = sm.u.s3.wofs[wave][n] + __popcll(mymask & ((1ull << lane) - 1ull));
      sm.sidx[pos] = (unsigned short)o;
    }
    if (o < 33) sm.sseg[o] = sm.u.s3.clsofs[o + 1];
  }
  __syncthreads();

  // ---- S4: layer-1 class-sums + divisor LIF + compaction ----
  {
    float S[32];
#pragma unroll
    for (int c = 0; c < 32; ++c) {
      int j0 = __builtin_amdgcn_readfirstlane((c == 0) ? 0 : sm.sseg[c - 1]);
      int j1 = __builtin_amdgcn_readfirstlane(sm.sseg[c]);
      float s = 0.f;
      for (int j = j0; j < j1; ++j)
        s += W1T[(size_t)sm.sidx[j] * 1024 + o];
      S[c] = s;
    }
    const float bias = b1[o];
    float v = 0.f;
    unsigned word = 0u;
#pragma unroll
    for (int t = 0; t < 32; ++t) {
      float cur = 0.f;
#pragma unroll
      for (int c = 1; c <= 32; ++c)
        if ((t + 1) % c == 0) cur += S[c - 1];   // compile-time divisor table
      float xc = cur + bias;
      v = v + (xc - v) * 0.5f;
      if (v >= 1.0f) { word |= 1u << t; v = 0.f; }
    }
    bool act = (word != 0u);
    unsigned long long m = __ballot(act);
    if (lane == 0) sm.u.s4.wtot[wave] = __popcll(m);
    __syncthreads();
    if (o == 0) {
      int s = 0;
#pragma unroll
      for (int i = 0; i < 16; ++i) { sm.u.s4.wbase[i] = s; s += sm.u.s4.wtot[i]; }
      sm.mtot = s;
    }
    __syncthreads();
    if (act) {
      int pos = sm.u.s4.wbase[wave] + __popcll(m & ((1ull << lane) - 1ull));
      sm.l2i[pos] = (unsigned)o;
      sm.l2w[pos] = word;
    }
  }
  __syncthreads();

  // ---- S5: layer-2 sparse FC + LIF + count ----
  {
    for (int i = o; i < 10240; i += 1024)
      sm.u.s5.sW2[(i >> 10) * 1025 + (i & 1023)] = W2[i];
    __syncthreads();
    const int mtot = sm.mtot;
    if (o < 320) {
      int t = o / 10, c = o - t * 10;
      float acc = 0.f;
      for (int j = 0; j < mtot; ++j) {
        unsigned wd = sm.l2w[j];
        float wv = sm.u.s5.sW2[c * 1025 + sm.l2i[j]];
        acc += ((wd >> t) & 1u) ? wv : 0.f;
      }
      sm.u.s5.scur[o] = acc;
    }
    __syncthreads();
    if (o < 10) {
      float v = 0.f, cnt2 = 0.f, bias = b2[o];
#pragma unroll
      for (int tt = 0; tt < 32; ++tt) {
        float xc = sm.u.s5.scur[tt * 10 + o] + bias;
        v = v + (xc - v) * 0.5f;
        if (v >= 1.0f) { cnt2 += 1.f; v = 0.f; }
      }
      out[(size_t)b * 10 + o] = cnt2;
    }
  }
}

// ---------------------------------------------------------------------------
extern "C" void kernel_launch(void* const* d_in, const int* in_sizes, int n_in,
                              void* d_out, int out_size, void* d_ws, size_t ws_size,
                              hipStream_t stream) {
  const float* x  = (const float*)d_in[0];   // [512,784]
  const float* W0 = (const float*)d_in[1];   // [1024,784]
  const float* b0 = (const float*)d_in[2];   // [1024]
  const float* W1 = (const float*)d_in[3];   // [1024,1024]
  const float* b1 = (const float*)d_in[4];   // [1024]
  const float* W2 = (const float*)d_in[5];   // [10,1024]
  const float* b2 = (const float*)d_in[6];   // [10]
  float* out = (float*)d_out;                // [512,10]

  char* ws = (char*)d_ws;
  size_t off = 0;
  auto alloc = [&](size_t bytes) -> char* {
    char* p = ws + off;
    off += (bytes + 255) & ~(size_t)255;
    return p;
  };
  __hip_bfloat16* Ax    = (__hip_bfloat16*)alloc((size_t)512 * 2400 * 2);   // 2.4 MB
  __hip_bfloat16* Bw    = (__hip_bfloat16*)alloc((size_t)1024 * 2400 * 2);  // 4.9 MB
  float*          Cpart = (float*)alloc((size_t)10 * 512 * 1024 * 4);       // 21 MB
  float*          W1T   = (float*)alloc((size_t)1024 * 1024 * 4);           // 4.2 MB
  (void)ws_size;

  prep_k<<<1200, 256, 0, stream>>>(x, W0, Ax, Bw);
  gemm0t_k<<<1344, 256, 0, stream>>>(Ax, Bw, W1, W1T, Cpart);
  tail_k<<<512, 1024, 0, stream>>>(Cpart, b0, W1T, b1, W2, b2, out);
}